// Round 2
// baseline (4446.096 us; speedup 1.0000x reference)
//
#include <hip/hip_runtime.h>
#include <hip/hip_cooperative_groups.h>

namespace cg = cooperative_groups;

#define B_ 1024
#define L_ 80
#define E_ 256
#define D_ 256
#define T_ 20
#define NS_ 4
#define NSYM_ 100

typedef __attribute__((ext_vector_type(8))) short short8;
typedef __attribute__((ext_vector_type(4))) float f32x4;

__device__ inline short f2b(float f) {
    unsigned u = __float_as_uint(f);
    unsigned r = (u + 0x7fffu + ((u >> 16) & 1u)) >> 16;
    return (short)r;
}
__device__ inline float b2f(short s) {
    return __uint_as_float(((unsigned)(unsigned short)s) << 16);
}

// ---------------- init / conversion kernels ----------------

__global__ void zero_k(unsigned* __restrict__ p, size_t n) {
    size_t i = (size_t)blockIdx.x * blockDim.x + threadIdx.x;
    size_t stride = (size_t)gridDim.x * blockDim.x;
    for (; i < n; i += stride) p[i] = 0u;
}

__global__ void f2b4_k(const float* __restrict__ src, short* __restrict__ dst, size_t n4) {
    size_t i = (size_t)blockIdx.x * blockDim.x + threadIdx.x;
    size_t stride = (size_t)gridDim.x * blockDim.x;
    for (; i < n4; i += stride) {
        float4 v = ((const float4*)src)[i];
        short4 o;
        o.x = f2b(v.x); o.y = f2b(v.y); o.z = f2b(v.z); o.w = f2b(v.w);
        ((short4*)dst)[i] = o;
    }
}

// split W [rows, 512] into two bf16 [rows, 256] halves
__global__ void split_k(const float* __restrict__ Wsrc, short* __restrict__ dstE,
                        short* __restrict__ dstH, int rows) {
    int id = blockIdx.x * 256 + threadIdx.x;
    if (id >= rows * 512) return;
    int rr = id >> 9, cc = id & 511;
    short v = f2b(Wsrc[id]);
    if (cc < 256) dstE[rr * 256 + cc] = v;
    else          dstH[rr * 256 + (cc - 256)] = v;
}

// build gate-interleaved [1024, 512] bf16 weights: row (4u+g) = [Wih[g*256+u,:] | Whh[g*256+u,:]]
__global__ void gatesW_k(const float* __restrict__ Wih, const float* __restrict__ Whh,
                         const float* __restrict__ bih, const float* __restrict__ bhh,
                         short* __restrict__ WgB, float* __restrict__ bg) {
    int id = blockIdx.x * 256 + threadIdx.x;   // < 524288
    int np = id >> 9, cc = id & 511;
    int u = np >> 2, g = np & 3;
    int srow = g * 256 + u;
    float v = (cc < 256) ? Wih[srow * 256 + cc] : Whh[srow * 256 + (cc - 256)];
    WgB[id] = f2b(v);
    if (id < 1024) {
        int u2 = id >> 2, g2 = id & 3;
        bg[id] = bih[g2 * 256 + u2] + bhh[g2 * 256 + u2];
    }
}

// embedding gather -> bf16 embB [T*B, D] with row r = t*B + b
__global__ void embed_k(const int* __restrict__ tsi, const float* __restrict__ common,
                        const float* __restrict__ syms, short* __restrict__ embB) {
    size_t id = (size_t)blockIdx.x * 256 + threadIdx.x;  // < T*B*D
    int d = (int)(id & 255);
    size_t r = id >> 8;
    int tt = (int)(r >> 10);      // B_ = 1024
    int b  = (int)(r & 1023);
    int idx = tsi[b * T_ + tt];
    float v;
    if (idx < NS_) {
        int i2 = idx < 0 ? 0 : idx;
        v = common[i2 * D_ + d];
    } else {
        int i2 = idx - NS_;
        if (i2 > NSYM_ - 1) i2 = NSYM_ - 1;
        v = syms[((size_t)b * NSYM_ + i2) * D_ + d];
    }
    embB[id] = f2b(v);
}

// ---------------- generic bf16 MFMA GEMM: C = act(A @ W^T + addend + bias) ----------------

__global__ __launch_bounds__(256) void gemm_k(
    const short* __restrict__ A, int lda,
    const short* __restrict__ W,
    const float* __restrict__ addend, int ldAdd,
    const float* __restrict__ bias,
    int act,
    float* __restrict__ outF, int ldoF,
    short* __restrict__ outB, int ldoB,
    int M, int N, int K)
{
    __shared__ alignas(16) short As[64][40];
    __shared__ alignas(16) short Ws[64][40];
    int m0 = blockIdx.x * 64, n0 = blockIdx.y * 64;
    int t = threadIdx.x;
    int w = t >> 6, l = t & 63, quad = l >> 4, lm = l & 15;
    int wm = (w >> 1) * 32, wn = (w & 1) * 32;
    f32x4 acc[2][2] = {};
    int rowL = t >> 2, c8 = (t & 3) * 8;
    for (int k0 = 0; k0 < K; k0 += 32) {
        uint4 av = *(const uint4*)(A + (size_t)(m0 + rowL) * lda + k0 + c8);
        uint4 wv = {0u, 0u, 0u, 0u};
        int wr = n0 + rowL;
        if (wr < N) wv = *(const uint4*)(W + (size_t)wr * K + k0 + c8);
        *(uint4*)&As[rowL][c8] = av;
        *(uint4*)&Ws[rowL][c8] = wv;
        __syncthreads();
        short8 af[2], wf[2];
        af[0] = *(const short8*)&As[wm + lm][quad * 8];
        af[1] = *(const short8*)&As[wm + 16 + lm][quad * 8];
        wf[0] = *(const short8*)&Ws[wn + lm][quad * 8];
        wf[1] = *(const short8*)&Ws[wn + 16 + lm][quad * 8];
        #pragma unroll
        for (int i = 0; i < 2; i++)
            #pragma unroll
            for (int j = 0; j < 2; j++)
                acc[i][j] = __builtin_amdgcn_mfma_f32_16x16x32_bf16(af[i], wf[j], acc[i][j], 0, 0, 0);
        __syncthreads();
    }
    #pragma unroll
    for (int i = 0; i < 2; i++)
        #pragma unroll
        for (int j = 0; j < 2; j++) {
            int col = n0 + wn + j * 16 + lm;
            if (col >= N) continue;
            float bval = bias ? bias[col] : 0.f;
            #pragma unroll
            for (int r = 0; r < 4; r++) {
                int row = m0 + wm + i * 16 + quad * 4 + r;
                float v = acc[i][j][r] + bval;
                if (addend) v += addend[(size_t)row * ldAdd + col];
                if (act == 1) v = fmaxf(v, 0.f);
                if (outF) outF[(size_t)row * ldoF + col] = v;
                if (outB) outB[(size_t)row * ldoB + col] = f2b(v);
            }
        }
}

// ---------------- persistent decode: shared structures ----------------

struct DecArgs {
    short* H1all;        // [(T+1)*B, 256] bf16; slot t = h1 entering step t
    const short* WaHB;   // [80, 256] bf16
    const float* awE;    // [T*B, 80]  (includes b_attn)
    const short* encW;   // [B, 80, 256] bf16 = enc @ WcA^T
    const float* combE;  // [T*B, 256] (includes b_comb)
    short* X0a; short* X0b; short* X1a; short* X1b;
    const short* Wg0; const float* bg0; float* c0;
    const short* Wg1; const float* bg1; float* c1;
};

struct SMGemm {
    alignas(16) short As[64][40];
    alignas(16) short Ws[64][40];
    float gS[64][68];
};
struct SMAttn {
    float awS[4][80];
    float apS[4][80];
};

// ---- phase A: attention (MFMA) + softmax + encW weighted sum + comb relu ----
// block owns 4 batch rows b0..b0+3; A-rows replicated x4 in the 16-row fragment.

__device__ inline void attn_body(const DecArgs& a, int tt, short* __restrict__ X0p, SMAttn& at)
{
    int t = threadIdx.x;
    int blk = blockIdx.x;
    int w = t >> 6, l = t & 63, quad = l >> 4, lm = l & 15;
    int b0 = blk << 2;
    {
        const short* H1t = a.H1all + (size_t)tt * (B_ * 256);
        int arow = b0 + (lm & 3);
        f32x4 acc0 = {}, acc1 = {};
        #pragma unroll
        for (int ks = 0; ks < 8; ks++) {
            int k0 = ks * 32 + quad * 8;
            short8 af = *(const short8*)(H1t + (size_t)arow * 256 + k0);
            short8 wf0 = *(const short8*)(a.WaHB + (size_t)(w * 16 + lm) * 256 + k0);
            acc0 = __builtin_amdgcn_mfma_f32_16x16x32_bf16(af, wf0, acc0, 0, 0, 0);
            if (w == 0) {
                short8 wf1 = *(const short8*)(a.WaHB + (size_t)(64 + lm) * 256 + k0);
                acc1 = __builtin_amdgcn_mfma_f32_16x16x32_bf16(af, wf1, acc1, 0, 0, 0);
            }
        }
        // C layout: col=lane&15, row=quad*4+r; rows replicate mod 4 -> b = b0 + r
        if (quad == 0) {
            const float* awEt = a.awE + ((size_t)tt * B_ + b0) * 80;
            #pragma unroll
            for (int r = 0; r < 4; r++) {
                at.awS[r][w * 16 + lm] = acc0[r] + awEt[(size_t)r * 80 + w * 16 + lm];
                if (w == 0)
                    at.awS[r][64 + lm] = acc1[r] + awEt[(size_t)r * 80 + 64 + lm];
            }
        }
    }
    __syncthreads();
    {
        int sub = w, lane = l;
        int b = b0 + sub;
        float aw0 = at.awS[sub][lane];
        float aw1 = at.awS[sub][64 + (lane & 15)];
        float mx = fmaxf(aw0, (lane < 16) ? aw1 : -1e30f);
        #pragma unroll
        for (int d = 1; d < 64; d <<= 1) mx = fmaxf(mx, __shfl_xor(mx, d));
        float e0 = __expf(aw0 - mx);
        float e1 = (lane < 16) ? __expf(aw1 - mx) : 0.f;
        float ssum = e0 + e1;
        #pragma unroll
        for (int d = 1; d < 64; d <<= 1) ssum += __shfl_xor(ssum, d);
        float inv = 1.f / ssum;
        at.apS[sub][lane] = e0 * inv;
        if (lane < 16) at.apS[sub][64 + lane] = e1 * inv;
        const short* ep = a.encW + (size_t)b * (80 * 256) + lane * 4;
        float o0 = 0.f, o1 = 0.f, o2 = 0.f, o3 = 0.f;
        #pragma unroll 8
        for (int ll = 0; ll < 80; ll++) {
            float apv = at.apS[sub][ll];
            short4 ev = *(const short4*)(ep + (size_t)ll * 256);
            o0 += apv * b2f(ev.x); o1 += apv * b2f(ev.y);
            o2 += apv * b2f(ev.z); o3 += apv * b2f(ev.w);
        }
        int d0 = lane * 4;
        const float* cE = a.combE + ((size_t)tt * B_ + b) * 256 + d0;
        short4 ov;
        ov.x = f2b(fmaxf(o0 + cE[0], 0.f));
        ov.y = f2b(fmaxf(o1 + cE[1], 0.f));
        ov.z = f2b(fmaxf(o2 + cE[2], 0.f));
        ov.w = f2b(fmaxf(o3 + cE[3], 0.f));
        *(short4*)(X0p + (size_t)b * 512 + d0) = ov;
    }
}

// ---- phase B/C: gates GEMM + fused LSTM cell (64x64 tile per block) ----

__device__ inline void gates_phase(
    const short* __restrict__ X, const short* __restrict__ Wg,
    const float* __restrict__ bg, float* __restrict__ c,
    short* __restrict__ hA, int ldA, int offA,
    short* __restrict__ hB2, int ldB2, int offB2,
    int m0, int n0, int t, SMGemm& s)
{
    int w = t >> 6, l = t & 63, quad = l >> 4, lm = l & 15;
    int wm = (w >> 1) * 32, wn = (w & 1) * 32;
    f32x4 acc[2][2] = {};
    int rowL = t >> 2, c8 = (t & 3) * 8;
    for (int k0 = 0; k0 < 512; k0 += 32) {
        *(uint4*)&s.As[rowL][c8] = *(const uint4*)(X + (size_t)(m0 + rowL) * 512 + k0 + c8);
        *(uint4*)&s.Ws[rowL][c8] = *(const uint4*)(Wg + (size_t)(n0 + rowL) * 512 + k0 + c8);
        __syncthreads();
        short8 af[2], wf[2];
        af[0] = *(const short8*)&s.As[wm + lm][quad * 8];
        af[1] = *(const short8*)&s.As[wm + 16 + lm][quad * 8];
        wf[0] = *(const short8*)&s.Ws[wn + lm][quad * 8];
        wf[1] = *(const short8*)&s.Ws[wn + 16 + lm][quad * 8];
        #pragma unroll
        for (int i = 0; i < 2; i++)
            #pragma unroll
            for (int j = 0; j < 2; j++)
                acc[i][j] = __builtin_amdgcn_mfma_f32_16x16x32_bf16(af[i], wf[j], acc[i][j], 0, 0, 0);
        __syncthreads();
    }
    #pragma unroll
    for (int i = 0; i < 2; i++)
        #pragma unroll
        for (int j = 0; j < 2; j++) {
            int col = wn + j * 16 + lm;
            float bval = bg[n0 + col];
            #pragma unroll
            for (int r = 0; r < 4; r++)
                s.gS[wm + i * 16 + quad * 4 + r][col] = acc[i][j][r] + bval;
        }
    __syncthreads();
    int U0 = n0 >> 2;
    for (int item = t; item < 1024; item += 256) {
        int ml = item >> 4, ul = item & 15;
        float iv = s.gS[ml][ul * 4 + 0];
        float fv = s.gS[ml][ul * 4 + 1];
        float gv = s.gS[ml][ul * 4 + 2];
        float ov = s.gS[ml][ul * 4 + 3];
        float si = 1.f / (1.f + __expf(-iv));
        float sf = 1.f / (1.f + __expf(-fv));
        float so = 1.f / (1.f + __expf(-ov));
        float tg = 2.f / (1.f + __expf(-2.f * gv)) - 1.f;
        int m = m0 + ml, u = U0 + ul;
        size_t ci = (size_t)m * 256 + u;
        float cn = sf * c[ci] + si * tg;
        float th = 2.f / (1.f + __expf(-2.f * cn)) - 1.f;
        float hn = so * th;
        c[ci] = cn;
        short hb = f2b(hn);
        hA[(size_t)m * ldA + offA + u] = hb;
        hB2[(size_t)m * ldB2 + offB2 + u] = hb;
    }
}

// ---- the persistent cooperative decode kernel: whole T loop, 3 grid syncs/step ----

__global__ __launch_bounds__(256, 1) void decode_k(DecArgs a)
{
    cg::grid_group grid = cg::this_grid();
    __shared__ union { SMGemm g; SMAttn at; } sm;
    int t = threadIdx.x;
    int blk = blockIdx.x;
    int m0 = (blk & 15) * 64, n0 = (blk >> 4) * 64;

    for (int tt = 0; tt < T_; tt++) {
        int p = tt & 1;
        short* X0p = p ? a.X0b : a.X0a;
        short* X0q = p ? a.X0a : a.X0b;
        short* X1p = p ? a.X1b : a.X1a;
        short* X1q = p ? a.X1a : a.X1b;

        attn_body(a, tt, X0p, sm.at);
        __threadfence();
        grid.sync();
        gates_phase(X0p, a.Wg0, a.bg0, a.c0, X0q, 512, 256, X1p, 512, 0, m0, n0, t, sm.g);
        __threadfence();
        grid.sync();
        gates_phase(X1p, a.Wg1, a.bg1, a.c1, X1q, 512, 256,
                    a.H1all + (size_t)(tt + 1) * (B_ * 256), 256, 0, m0, n0, t, sm.g);
        __threadfence();
        grid.sync();
    }
}

// ---- fallback wrappers (non-cooperative path, 3 launches/step) ----

__global__ __launch_bounds__(256) void phaseA_k(DecArgs a, int tt, short* __restrict__ X0p) {
    __shared__ SMAttn at;
    attn_body(a, tt, X0p, at);
}

__global__ __launch_bounds__(256) void phaseG_k(
    const short* __restrict__ X, const short* __restrict__ Wg,
    const float* __restrict__ bg, float* __restrict__ c,
    short* __restrict__ hA, int ldA, int offA,
    short* __restrict__ hB2, int ldB2, int offB2)
{
    __shared__ SMGemm g;
    int blk = blockIdx.x;
    gates_phase(X, Wg, bg, c, hA, ldA, offA, hB2, ldB2, offB2,
                (blk & 15) * 64, (blk >> 4) * 64, threadIdx.x, g);
}

// ---------------- batched out GEMM + fused log-softmax ----------------

__global__ __launch_bounds__(256) void out_k(
    const short* __restrict__ h1B,     // [T*B, 256] bf16 (H1all slots 1..T)
    const short* __restrict__ WoB,
    const float* __restrict__ b_out,
    float* __restrict__ outT)          // [T*B, 256]
{
    __shared__ alignas(16) short As[32][40];
    __shared__ alignas(16) short Ws[256][40];
    __shared__ float oS[32][260];
    int m0 = blockIdx.x * 32;
    int t = threadIdx.x, w = t >> 6, l = t & 63, quad = l >> 4, lm = l & 15;
    int wm = (w >> 1) * 16, wn = (w & 1) * 128;
    f32x4 acc[8] = {};
    for (int k0 = 0; k0 < 256; k0 += 32) {
        if (t < 128) {
            int rr = t >> 2, cc = (t & 3) * 8;
            *(uint4*)&As[rr][cc] = *(const uint4*)(h1B + (size_t)(m0 + rr) * 256 + k0 + cc);
        }
        for (int cch = t; cch < 1024; cch += 256) {
            int rr = cch >> 2, cc = (cch & 3) * 8;
            *(uint4*)&Ws[rr][cc] = *(const uint4*)(WoB + (size_t)rr * 256 + k0 + cc);
        }
        __syncthreads();
        short8 af = *(const short8*)&As[wm + lm][quad * 8];
        #pragma unroll
        for (int j = 0; j < 8; j++) {
            short8 wf = *(const short8*)&Ws[wn + j * 16 + lm][quad * 8];
            acc[j] = __builtin_amdgcn_mfma_f32_16x16x32_bf16(af, wf, acc[j], 0, 0, 0);
        }
        __syncthreads();
    }
    #pragma unroll
    for (int j = 0; j < 8; j++)
        #pragma unroll
        for (int r = 0; r < 4; r++)
            oS[wm + quad * 4 + r][wn + j * 16 + lm] = acc[j][r] + b_out[wn + j * 16 + lm];
    __syncthreads();
    int row = t >> 3, q = t & 7;
    float mx = -1e30f;
    for (int i = q * 32; i < q * 32 + 32; i++) mx = fmaxf(mx, oS[row][i]);
    mx = fmaxf(mx, __shfl_xor(mx, 1));
    mx = fmaxf(mx, __shfl_xor(mx, 2));
    mx = fmaxf(mx, __shfl_xor(mx, 4));
    float s = 0.f;
    for (int i = q * 32; i < q * 32 + 32; i++) s += __expf(oS[row][i] - mx);
    s += __shfl_xor(s, 1); s += __shfl_xor(s, 2); s += __shfl_xor(s, 4);
    float lg = mx + logf(s);
    float* orow = outT + (size_t)(m0 + row) * 256;
    for (int i = q * 32; i < q * 32 + 32; i++) orow[i] = oS[row][i] - lg;
}

// ---------------- host ----------------

extern "C" void kernel_launch(void* const* d_in, const int* in_sizes, int n_in,
                              void* d_out, int out_size, void* d_ws, size_t ws_size,
                              hipStream_t stream) {
    const float* encF    = (const float*)d_in[0];
    const float* syms    = (const float*)d_in[1];
    const int*   tsi     = (const int*)d_in[2];
    const float* commonE = (const float*)d_in[3];
    const float* W_attn  = (const float*)d_in[4];
    const float* b_attn  = (const float*)d_in[5];
    const float* W_comb  = (const float*)d_in[6];
    const float* b_comb  = (const float*)d_in[7];
    const float* Wih0    = (const float*)d_in[8];
    const float* Whh0    = (const float*)d_in[9];
    const float* bih0    = (const float*)d_in[10];
    const float* bhh0    = (const float*)d_in[11];
    const float* Wih1    = (const float*)d_in[12];
    const float* Whh1    = (const float*)d_in[13];
    const float* bih1    = (const float*)d_in[14];
    const float* bhh1    = (const float*)d_in[15];
    const float* W_out   = (const float*)d_in[16];
    const float* b_out   = (const float*)d_in[17];
    float* out = (float*)d_out;

    char* base = (char*)d_ws;
    size_t off = 0;
    auto alloc = [&](size_t bytes) -> char* {
        char* p = base + off;
        off += (bytes + 255) & ~(size_t)255;
        return p;
    };
    // zero-region first (contiguous): c0, c1, X0a, X1a, H1all slot 0
    float* c0    = (float*)alloc((size_t)B_ * D_ * 4);
    float* c1    = (float*)alloc((size_t)B_ * D_ * 4);
    short* X0a   = (short*)alloc((size_t)B_ * 512 * 2);
    short* X1a   = (short*)alloc((size_t)B_ * 512 * 2);
    short* H1all = (short*)alloc((size_t)(T_ + 1) * B_ * D_ * 2);
    size_t zeroBytes = (size_t)((char*)H1all - base) + (size_t)B_ * D_ * 2;
    short* X0b   = (short*)alloc((size_t)B_ * 512 * 2);
    short* X1b   = (short*)alloc((size_t)B_ * 512 * 2);
    float* awE   = (float*)alloc((size_t)T_ * B_ * L_ * 4);
    float* combE = (float*)alloc((size_t)T_ * B_ * D_ * 4);
    short* embB  = (short*)alloc((size_t)T_ * B_ * D_ * 2);
    short* WaEB  = (short*)alloc((size_t)L_ * D_ * 2);
    short* WaHB  = (short*)alloc((size_t)L_ * D_ * 2);
    short* WcEB  = (short*)alloc((size_t)D_ * D_ * 2);
    short* WcAB  = (short*)alloc((size_t)D_ * E_ * 2);
    short* Wg0B  = (short*)alloc((size_t)1024 * 512 * 2);
    short* Wg1B  = (short*)alloc((size_t)1024 * 512 * 2);
    short* WoutB = (short*)alloc((size_t)D_ * E_ * 2);
    float* bg0   = (float*)alloc(1024 * 4);
    float* bg1   = (float*)alloc(1024 * 4);
    short* encB  = (short*)alloc((size_t)B_ * L_ * E_ * 2);
    short* encW  = (short*)alloc((size_t)B_ * L_ * D_ * 2);  // enc @ W_combA^T, bf16
    (void)ws_size; (void)in_sizes; (void)n_in; (void)out_size;

    // ---- init / precompute (off the serial path) ----
    zero_k<<<2048, 256, 0, stream>>>((unsigned*)base, zeroBytes / 4);
    f2b4_k<<<4096, 256, 0, stream>>>(encF, encB, (size_t)B_ * L_ * E_ / 4);
    f2b4_k<<<64, 256, 0, stream>>>(W_out, WoutB, (size_t)D_ * E_ / 4);
    split_k<<<(80 * 512) / 256, 256, 0, stream>>>(W_attn, WaEB, WaHB, 80);
    split_k<<<(256 * 512) / 256, 256, 0, stream>>>(W_comb, WcEB, WcAB, 256);
    gatesW_k<<<2048, 256, 0, stream>>>(Wih0, Whh0, bih0, bhh0, Wg0B, bg0);
    gatesW_k<<<2048, 256, 0, stream>>>(Wih1, Whh1, bih1, bhh1, Wg1B, bg1);
    embed_k<<<(T_ * B_ * D_) / 256, 256, 0, stream>>>(tsi, commonE, syms, embB);
    // awE[t,b,l] = emb @ WaE^T + b_attn
    gemm_k<<<dim3(320, 2), 256, 0, stream>>>(embB, 256, WaEB, nullptr, 0, b_attn, 0,
                                             awE, 80, nullptr, 0, 20480, 80, 256);
    // combE[t,b,d] = emb @ WcE^T + b_comb  (b_comb folded in)
    gemm_k<<<dim3(320, 4), 256, 0, stream>>>(embB, 256, WcEB, nullptr, 0, b_comb, 0,
                                             combE, 256, nullptr, 0, 20480, 256, 256);
    // encW[b,l,:] = enc[b,l,:] @ WcA^T
    gemm_k<<<dim3(1280, 4), 256, 0, stream>>>(encB, 256, WcAB, nullptr, 0, nullptr, 0,
                                              nullptr, 0, encW, 256, 81920, 256, 256);

    // ---- persistent cooperative decode (3 grid syncs per timestep) ----
    DecArgs da;
    da.H1all = H1all; da.WaHB = WaHB; da.awE = awE; da.encW = encW; da.combE = combE;
    da.X0a = X0a; da.X0b = X0b; da.X1a = X1a; da.X1b = X1b;
    da.Wg0 = Wg0B; da.bg0 = bg0; da.c0 = c0;
    da.Wg1 = Wg1B; da.bg1 = bg1; da.c1 = c1;
    void* kargs[] = { &da };
    hipError_t ce = hipLaunchCooperativeKernel(reinterpret_cast<void*>(decode_k),
                                               dim3(256), dim3(256), kargs, 0, stream);
    if (ce != hipSuccess) {
        // fallback: same phases as separate launches
        for (int tt = 0; tt < T_; tt++) {
            int p = tt & 1;
            short* X0p = p ? X0b : X0a;
            short* X0q = p ? X0a : X0b;
            short* X1p = p ? X1b : X1a;
            short* X1q = p ? X1a : X1b;
            phaseA_k<<<256, 256, 0, stream>>>(da, tt, X0p);
            phaseG_k<<<256, 256, 0, stream>>>(X0p, Wg0B, bg0, c0, X0q, 512, 256, X1p, 512, 0);
            phaseG_k<<<256, 256, 0, stream>>>(X1p, Wg1B, bg1, c1, X1q, 512, 256,
                                              H1all + (size_t)(tt + 1) * B_ * D_, 256, 0);
        }
    }
    // ---- batched output projection + log-softmax over all T*B rows ----
    out_k<<<640, 256, 0, stream>>>(H1all + (size_t)B_ * D_, WoutB, b_out, out);
}

// Round 3
// 2974.006 us; speedup vs baseline: 1.4950x; 1.4950x over previous
//
#include <hip/hip_runtime.h>

#define B_ 1024
#define L_ 80
#define E_ 256
#define D_ 256
#define T_ 20
#define NS_ 4
#define NSYM_ 100

#define ROWS 16      // batch rows per decode block
#define NBLK 64      // B_ / ROWS
#define XP 520       // padded LDS row stride (shorts) for [rows][512] X buffers
#define GP 260       // padded LDS row stride (floats) for gate staging

typedef __attribute__((ext_vector_type(8))) short short8;
typedef __attribute__((ext_vector_type(4))) float f32x4;

__device__ inline short f2b(float f) {
    unsigned u = __float_as_uint(f);
    unsigned r = (u + 0x7fffu + ((u >> 16) & 1u)) >> 16;
    return (short)r;
}
__device__ inline float b2f(short s) {
    return __uint_as_float(((unsigned)(unsigned short)s) << 16);
}

// ---------------- init / conversion kernels ----------------

__global__ void f2b4_k(const float* __restrict__ src, short* __restrict__ dst, size_t n4) {
    size_t i = (size_t)blockIdx.x * blockDim.x + threadIdx.x;
    size_t stride = (size_t)gridDim.x * blockDim.x;
    for (; i < n4; i += stride) {
        float4 v = ((const float4*)src)[i];
        short4 o;
        o.x = f2b(v.x); o.y = f2b(v.y); o.z = f2b(v.z); o.w = f2b(v.w);
        ((short4*)dst)[i] = o;
    }
}

// split W [rows, 512] into two bf16 [rows, 256] halves
__global__ void split_k(const float* __restrict__ Wsrc, short* __restrict__ dstE,
                        short* __restrict__ dstH, int rows) {
    int id = blockIdx.x * 256 + threadIdx.x;
    if (id >= rows * 512) return;
    int rr = id >> 9, cc = id & 511;
    short v = f2b(Wsrc[id]);
    if (cc < 256) dstE[rr * 256 + cc] = v;
    else          dstH[rr * 256 + (cc - 256)] = v;
}

// build gate-interleaved [1024, 512] bf16 weights: row (4u+g) = [Wih[g*256+u,:] | Whh[g*256+u,:]]
__global__ void gatesW_k(const float* __restrict__ Wih, const float* __restrict__ Whh,
                         const float* __restrict__ bih, const float* __restrict__ bhh,
                         short* __restrict__ WgB, float* __restrict__ bg) {
    int id = blockIdx.x * 256 + threadIdx.x;   // < 524288
    int np = id >> 9, cc = id & 511;
    int u = np >> 2, g = np & 3;
    int srow = g * 256 + u;
    float v = (cc < 256) ? Wih[srow * 256 + cc] : Whh[srow * 256 + (cc - 256)];
    WgB[id] = f2b(v);
    if (id < 1024) {
        int u2 = id >> 2, g2 = id & 3;
        bg[id] = bih[g2 * 256 + u2] + bhh[g2 * 256 + u2];
    }
}

// embedding gather -> bf16 embB [T*B, D] with row r = t*B + b
__global__ void embed_k(const int* __restrict__ tsi, const float* __restrict__ common,
                        const float* __restrict__ syms, short* __restrict__ embB) {
    size_t id = (size_t)blockIdx.x * 256 + threadIdx.x;  // < T*B*D
    int d = (int)(id & 255);
    size_t r = id >> 8;
    int tt = (int)(r >> 10);      // B_ = 1024
    int b  = (int)(r & 1023);
    int idx = tsi[b * T_ + tt];
    float v;
    if (idx < NS_) {
        int i2 = idx < 0 ? 0 : idx;
        v = common[i2 * D_ + d];
    } else {
        int i2 = idx - NS_;
        if (i2 > NSYM_ - 1) i2 = NSYM_ - 1;
        v = syms[((size_t)b * NSYM_ + i2) * D_ + d];
    }
    embB[id] = f2b(v);
}

// ---------------- generic bf16 MFMA GEMM: C = act(A @ W^T + addend + bias) ----------------

__global__ __launch_bounds__(256) void gemm_k(
    const short* __restrict__ A, int lda,
    const short* __restrict__ W,
    const float* __restrict__ addend, int ldAdd,
    const float* __restrict__ bias,
    int act,
    float* __restrict__ outF, int ldoF,
    short* __restrict__ outB, int ldoB,
    int M, int N, int K)
{
    __shared__ alignas(16) short As[64][40];
    __shared__ alignas(16) short Ws[64][40];
    int m0 = blockIdx.x * 64, n0 = blockIdx.y * 64;
    int t = threadIdx.x;
    int w = t >> 6, l = t & 63, quad = l >> 4, lm = l & 15;
    int wm = (w >> 1) * 32, wn = (w & 1) * 32;
    f32x4 acc[2][2] = {};
    int rowL = t >> 2, c8 = (t & 3) * 8;
    for (int k0 = 0; k0 < K; k0 += 32) {
        uint4 av = *(const uint4*)(A + (size_t)(m0 + rowL) * lda + k0 + c8);
        uint4 wv = {0u, 0u, 0u, 0u};
        int wr = n0 + rowL;
        if (wr < N) wv = *(const uint4*)(W + (size_t)wr * K + k0 + c8);
        *(uint4*)&As[rowL][c8] = av;
        *(uint4*)&Ws[rowL][c8] = wv;
        __syncthreads();
        short8 af[2], wf[2];
        af[0] = *(const short8*)&As[wm + lm][quad * 8];
        af[1] = *(const short8*)&As[wm + 16 + lm][quad * 8];
        wf[0] = *(const short8*)&Ws[wn + lm][quad * 8];
        wf[1] = *(const short8*)&Ws[wn + 16 + lm][quad * 8];
        #pragma unroll
        for (int i = 0; i < 2; i++)
            #pragma unroll
            for (int j = 0; j < 2; j++)
                acc[i][j] = __builtin_amdgcn_mfma_f32_16x16x32_bf16(af[i], wf[j], acc[i][j], 0, 0, 0);
        __syncthreads();
    }
    #pragma unroll
    for (int i = 0; i < 2; i++)
        #pragma unroll
        for (int j = 0; j < 2; j++) {
            int col = n0 + wn + j * 16 + lm;
            if (col >= N) continue;
            float bval = bias ? bias[col] : 0.f;
            #pragma unroll
            for (int r = 0; r < 4; r++) {
                int row = m0 + wm + i * 16 + quad * 4 + r;
                float v = acc[i][j][r] + bval;
                if (addend) v += addend[(size_t)row * ldAdd + col];
                if (act == 1) v = fmaxf(v, 0.f);
                if (outF) outF[(size_t)row * ldoF + col] = v;
                if (outB) outB[(size_t)row * ldoB + col] = f2b(v);
            }
        }
}

// ---------------- batch-local persistent decode ----------------
// Each block owns ROWS=16 batch rows and runs all T steps privately.
// h0/h1 in LDS, c0/c1 in registers; weights streamed from L2; NO grid syncs.

struct DecArgs {
    short* H1all;        // [(T+1)*B, 256] bf16; slot t+1 = h1 after step t
    const short* WaHB;   // [80, 256] bf16
    const float* awE;    // [T*B, 80]  (includes b_attn)
    const short* encW;   // [B, 80, 256] bf16 = enc @ WcA^T
    const float* combE;  // [T*B, 256] (includes b_comb)
    const short* Wg0; const float* bg0;
    const short* Wg1; const float* bg1;
};

// gates GEMM (16 x 1024, K=512) + LSTM cell for this block's 16 rows.
// Wave w computes gate cols [256w, 256w+256): 16 n-tiles, wf loaded directly from global.
__device__ inline void layer_lstm(
    const short (*X)[XP],            // [16][512] bf16 input = [x | h_prev] (LDS)
    const short* __restrict__ Wg,    // [1024][512] bf16 gate-interleaved
    const float* __restrict__ bg,    // [1024]
    float* creg,                     // [ROWS] per-lane cell state (unit u = 64w + l)
    float (*gSv)[GP],                // wave-private [16][GP] staging
    short (*Hd1)[XP], int off1,      // LDS h dest 1
    short (*Hd2)[XP], int off2,      // LDS h dest 2 (nullptr ok)
    short* __restrict__ gdst,        // global h dest (nullptr ok), row stride 256
    int w, int l, int quad, int lm)
{
    f32x4 acc[16] = {};
    #pragma unroll 4
    for (int k0s = 0; k0s < 16; k0s++) {
        int k0 = k0s * 32;
        short8 af = *(const short8*)&X[lm][k0 + quad * 8];
        #pragma unroll
        for (int j = 0; j < 16; j++) {
            short8 wf = *(const short8*)(Wg + (size_t)(w * 256 + j * 16 + lm) * 512 + k0 + quad * 8);
            acc[j] = __builtin_amdgcn_mfma_f32_16x16x32_bf16(af, wf, acc[j], 0, 0, 0);
        }
    }
    __syncthreads();   // all waves done reading X before h writes overwrite X regions
    #pragma unroll
    for (int j = 0; j < 16; j++) {
        float bv = bg[w * 256 + j * 16 + lm];
        #pragma unroll
        for (int r = 0; r < 4; r++)
            gSv[quad * 4 + r][j * 16 + lm] = acc[j][r] + bv;
    }
    // wave-private staging -> per-lane LSTM (unit u = 64w + l; gates i,f,g,o contiguous)
    int u = w * 64 + l;
    #pragma unroll
    for (int row = 0; row < ROWS; row++) {
        float4 g4 = *(const float4*)&gSv[row][l * 4];
        float si = 1.f / (1.f + __expf(-g4.x));
        float sf = 1.f / (1.f + __expf(-g4.y));
        float tg = 2.f / (1.f + __expf(-2.f * g4.z)) - 1.f;
        float so = 1.f / (1.f + __expf(-g4.w));
        float cn = sf * creg[row] + si * tg;
        creg[row] = cn;
        float hn = so * (2.f / (1.f + __expf(-2.f * cn)) - 1.f);
        short hb = f2b(hn);
        Hd1[row][off1 + u] = hb;
        if (Hd2) Hd2[row][off2 + u] = hb;
        if (gdst) gdst[(size_t)row * 256 + u] = hb;
    }
    __syncthreads();   // h visible to all waves for the next phase
}

__global__ __launch_bounds__(256, 1) void decode_k(DecArgs a)
{
    __shared__ short X0[ROWS][XP];        // [comb | h0_prev]
    __shared__ short X1[ROWS][XP];        // [h0   | h1_prev]
    __shared__ float gS[4][ROWS][GP];     // per-wave gate staging
    __shared__ float awS[ROWS][80];
    __shared__ float apS[ROWS][80];

    int t = threadIdx.x, w = t >> 6, l = t & 63, quad = l >> 4, lm = l & 15;
    int b0 = blockIdx.x * ROWS;

    for (int i = t; i < ROWS * XP; i += 256) { (&X0[0][0])[i] = 0; (&X1[0][0])[i] = 0; }
    float c0r[ROWS], c1r[ROWS];
    #pragma unroll
    for (int i = 0; i < ROWS; i++) { c0r[i] = 0.f; c1r[i] = 0.f; }
    __syncthreads();

    for (int tt = 0; tt < T_; tt++) {
        // ---- attention scores: aw = h1_prev @ WaH^T + awE (16x80 via MFMA) ----
        {
            f32x4 acc0 = {}, acc1 = {};
            #pragma unroll
            for (int ks = 0; ks < 8; ks++) {
                int k0 = ks * 32 + quad * 8;
                short8 af = *(const short8*)&X1[lm][256 + k0];
                short8 wf0 = *(const short8*)(a.WaHB + (size_t)(w * 16 + lm) * 256 + k0);
                acc0 = __builtin_amdgcn_mfma_f32_16x16x32_bf16(af, wf0, acc0, 0, 0, 0);
                if (w == 0) {
                    short8 wf1 = *(const short8*)(a.WaHB + (size_t)(64 + lm) * 256 + k0);
                    acc1 = __builtin_amdgcn_mfma_f32_16x16x32_bf16(af, wf1, acc1, 0, 0, 0);
                }
            }
            const float* awEt = a.awE + ((size_t)tt * B_ + b0) * 80;
            #pragma unroll
            for (int r = 0; r < 4; r++) {
                int row = quad * 4 + r;
                awS[row][w * 16 + lm] = acc0[r] + awEt[(size_t)row * 80 + w * 16 + lm];
                if (w == 0)
                    awS[row][64 + lm] = acc1[r] + awEt[(size_t)row * 80 + 64 + lm];
            }
        }
        __syncthreads();
        // ---- softmax over 80 (wave w: rows 4w..4w+3; one quad-group of 16 lanes per row) ----
        {
            int row = w * 4 + quad;
            float v[5];
            float mx = -1e30f;
            #pragma unroll
            for (int j = 0; j < 5; j++) { v[j] = awS[row][lm + 16 * j]; mx = fmaxf(mx, v[j]); }
            #pragma unroll
            for (int d = 1; d < 16; d <<= 1) mx = fmaxf(mx, __shfl_xor(mx, d));
            float s = 0.f;
            #pragma unroll
            for (int j = 0; j < 5; j++) { v[j] = __expf(v[j] - mx); s += v[j]; }
            #pragma unroll
            for (int d = 1; d < 16; d <<= 1) s += __shfl_xor(s, d);
            float inv = 1.f / s;
            #pragma unroll
            for (int j = 0; j < 5; j++) apS[row][lm + 16 * j] = v[j] * inv;
        }
        // ---- apply + comb: comb = relu(sum_l ap[l]*encW[b,l,:] + combE) -> X0[:,0:256] ----
        {
            #pragma unroll
            for (int r_ = 0; r_ < 4; r_++) {
                int row = w * 4 + r_;
                int b = b0 + row;
                const short* ep = a.encW + ((size_t)b * 80) * 256 + l * 4;
                float o0 = 0.f, o1 = 0.f, o2 = 0.f, o3 = 0.f;
                #pragma unroll 8
                for (int ll = 0; ll < 80; ll++) {
                    float apv = apS[row][ll];
                    short4 ev = *(const short4*)(ep + (size_t)ll * 256);
                    o0 += apv * b2f(ev.x); o1 += apv * b2f(ev.y);
                    o2 += apv * b2f(ev.z); o3 += apv * b2f(ev.w);
                }
                float4 cE = *(const float4*)(a.combE + ((size_t)tt * B_ + b) * 256 + l * 4);
                short4 ov;
                ov.x = f2b(fmaxf(o0 + cE.x, 0.f));
                ov.y = f2b(fmaxf(o1 + cE.y, 0.f));
                ov.z = f2b(fmaxf(o2 + cE.z, 0.f));
                ov.w = f2b(fmaxf(o3 + cE.w, 0.f));
                *(short4*)&X0[row][l * 4] = ov;
            }
        }
        __syncthreads();
        // ---- layer 0: X0 -> h0 (into X1[:,0:256] and X0[:,256:512] for next step) ----
        layer_lstm(X0, a.Wg0, a.bg0, c0r, gS[w],
                   X1, 0, X0, 256, nullptr, w, l, quad, lm);
        // ---- layer 1: X1 -> h1 (into X1[:,256:512] and global H1all slot tt+1) ----
        layer_lstm(X1, a.Wg1, a.bg1, c1r, gS[w],
                   X1, 256, nullptr, 0,
                   a.H1all + ((size_t)(tt + 1) * B_ + b0) * 256, w, l, quad, lm);
    }
}

// ---------------- batched out GEMM + fused log-softmax ----------------

__global__ __launch_bounds__(256) void out_k(
    const short* __restrict__ h1B,     // [T*B, 256] bf16 (H1all slots 1..T)
    const short* __restrict__ WoB,
    const float* __restrict__ b_out,
    float* __restrict__ outT)          // [T*B, 256]
{
    __shared__ alignas(16) short As[32][40];
    __shared__ alignas(16) short Ws[256][40];
    __shared__ float oS[32][260];
    int m0 = blockIdx.x * 32;
    int t = threadIdx.x, w = t >> 6, l = t & 63, quad = l >> 4, lm = l & 15;
    int wm = (w >> 1) * 16, wn = (w & 1) * 128;
    f32x4 acc[8] = {};
    for (int k0 = 0; k0 < 256; k0 += 32) {
        if (t < 128) {
            int rr = t >> 2, cc = (t & 3) * 8;
            *(uint4*)&As[rr][cc] = *(const uint4*)(h1B + (size_t)(m0 + rr) * 256 + k0 + cc);
        }
        for (int cch = t; cch < 1024; cch += 256) {
            int rr = cch >> 2, cc = (cch & 3) * 8;
            *(uint4*)&Ws[rr][cc] = *(const uint4*)(WoB + (size_t)rr * 256 + k0 + cc);
        }
        __syncthreads();
        short8 af = *(const short8*)&As[wm + lm][quad * 8];
        #pragma unroll
        for (int j = 0; j < 8; j++) {
            short8 wf = *(const short8*)&Ws[wn + j * 16 + lm][quad * 8];
            acc[j] = __builtin_amdgcn_mfma_f32_16x16x32_bf16(af, wf, acc[j], 0, 0, 0);
        }
        __syncthreads();
    }
    #pragma unroll
    for (int j = 0; j < 8; j++)
        #pragma unroll
        for (int r = 0; r < 4; r++)
            oS[wm + quad * 4 + r][wn + j * 16 + lm] = acc[j][r] + b_out[wn + j * 16 + lm];
    __syncthreads();
    int row = t >> 3, q = t & 7;
    float mx = -1e30f;
    for (int i = q * 32; i < q * 32 + 32; i++) mx = fmaxf(mx, oS[row][i]);
    mx = fmaxf(mx, __shfl_xor(mx, 1));
    mx = fmaxf(mx, __shfl_xor(mx, 2));
    mx = fmaxf(mx, __shfl_xor(mx, 4));
    float s = 0.f;
    for (int i = q * 32; i < q * 32 + 32; i++) s += __expf(oS[row][i] - mx);
    s += __shfl_xor(s, 1); s += __shfl_xor(s, 2); s += __shfl_xor(s, 4);
    float lg = mx + logf(s);
    float* orow = outT + (size_t)(m0 + row) * 256;
    for (int i = q * 32; i < q * 32 + 32; i++) orow[i] = oS[row][i] - lg;
}

// ---------------- host ----------------

extern "C" void kernel_launch(void* const* d_in, const int* in_sizes, int n_in,
                              void* d_out, int out_size, void* d_ws, size_t ws_size,
                              hipStream_t stream) {
    const float* encF    = (const float*)d_in[0];
    const float* syms    = (const float*)d_in[1];
    const int*   tsi     = (const int*)d_in[2];
    const float* commonE = (const float*)d_in[3];
    const float* W_attn  = (const float*)d_in[4];
    const float* b_attn  = (const float*)d_in[5];
    const float* W_comb  = (const float*)d_in[6];
    const float* b_comb  = (const float*)d_in[7];
    const float* Wih0    = (const float*)d_in[8];
    const float* Whh0    = (const float*)d_in[9];
    const float* bih0    = (const float*)d_in[10];
    const float* bhh0    = (const float*)d_in[11];
    const float* Wih1    = (const float*)d_in[12];
    const float* Whh1    = (const float*)d_in[13];
    const float* bih1    = (const float*)d_in[14];
    const float* bhh1    = (const float*)d_in[15];
    const float* W_out   = (const float*)d_in[16];
    const float* b_out   = (const float*)d_in[17];
    float* out = (float*)d_out;

    char* base = (char*)d_ws;
    size_t off = 0;
    auto alloc = [&](size_t bytes) -> char* {
        char* p = base + off;
        off += (bytes + 255) & ~(size_t)255;
        return p;
    };
    short* H1all = (short*)alloc((size_t)(T_ + 1) * B_ * D_ * 2);
    float* awE   = (float*)alloc((size_t)T_ * B_ * L_ * 4);
    float* combE = (float*)alloc((size_t)T_ * B_ * D_ * 4);
    short* embB  = (short*)alloc((size_t)T_ * B_ * D_ * 2);
    short* WaEB  = (short*)alloc((size_t)L_ * D_ * 2);
    short* WaHB  = (short*)alloc((size_t)L_ * D_ * 2);
    short* WcEB  = (short*)alloc((size_t)D_ * D_ * 2);
    short* WcAB  = (short*)alloc((size_t)D_ * E_ * 2);
    short* Wg0B  = (short*)alloc((size_t)1024 * 512 * 2);
    short* Wg1B  = (short*)alloc((size_t)1024 * 512 * 2);
    short* WoutB = (short*)alloc((size_t)D_ * E_ * 2);
    float* bg0   = (float*)alloc(1024 * 4);
    float* bg1   = (float*)alloc(1024 * 4);
    short* encB  = (short*)alloc((size_t)B_ * L_ * E_ * 2);
    short* encW  = (short*)alloc((size_t)B_ * L_ * D_ * 2);  // enc @ W_combA^T, bf16
    (void)ws_size; (void)in_sizes; (void)n_in; (void)out_size;

    // ---- init / precompute (off the serial path; no zeroing needed) ----
    f2b4_k<<<4096, 256, 0, stream>>>(encF, encB, (size_t)B_ * L_ * E_ / 4);
    f2b4_k<<<64, 256, 0, stream>>>(W_out, WoutB, (size_t)D_ * E_ / 4);
    split_k<<<(80 * 512) / 256, 256, 0, stream>>>(W_attn, WaEB, WaHB, 80);
    split_k<<<(256 * 512) / 256, 256, 0, stream>>>(W_comb, WcEB, WcAB, 256);
    gatesW_k<<<2048, 256, 0, stream>>>(Wih0, Whh0, bih0, bhh0, Wg0B, bg0);
    gatesW_k<<<2048, 256, 0, stream>>>(Wih1, Whh1, bih1, bhh1, Wg1B, bg1);
    embed_k<<<(T_ * B_ * D_) / 256, 256, 0, stream>>>(tsi, commonE, syms, embB);
    // awE[t,b,l] = emb @ WaE^T + b_attn
    gemm_k<<<dim3(320, 2), 256, 0, stream>>>(embB, 256, WaEB, nullptr, 0, b_attn, 0,
                                             awE, 80, nullptr, 0, 20480, 80, 256);
    // combE[t,b,d] = emb @ WcE^T + b_comb
    gemm_k<<<dim3(320, 4), 256, 0, stream>>>(embB, 256, WcEB, nullptr, 0, b_comb, 0,
                                             combE, 256, nullptr, 0, 20480, 256, 256);
    // encW[b,l,:] = enc[b,l,:] @ WcA^T
    gemm_k<<<dim3(1280, 4), 256, 0, stream>>>(encB, 256, WcAB, nullptr, 0, nullptr, 0,
                                              nullptr, 0, encW, 256, 81920, 256, 256);

    // ---- batch-local persistent decode: ONE plain launch, no grid syncs ----
    DecArgs da;
    da.H1all = H1all; da.WaHB = WaHB; da.awE = awE; da.encW = encW; da.combE = combE;
    da.Wg0 = Wg0B; da.bg0 = bg0;
    da.Wg1 = Wg1B; da.bg1 = bg1;
    decode_k<<<NBLK, 256, 0, stream>>>(da);

    // ---- batched output projection + log-softmax over all T*B rows ----
    out_k<<<640, 256, 0, stream>>>(H1all + (size_t)B_ * D_, WoutB, b_out, out);
}